// Round 1
// baseline (27.908 us; speedup 1.0000x reference)
//
#include <hip/hip_runtime.h>
#include <math.h>

#define BLOCK 256
#define WAVES_PER_BLOCK (BLOCK / 64)
#define GRID 2048
#define K 2048

// Phase 1: each wave computes ssq of whole rows (grid-stride over rows),
// accumulates (ssq-1)^2, block-reduces, writes one partial per block.
__global__ __launch_bounds__(BLOCK) void row_ssq_kernel(
    const float* __restrict__ d, float* __restrict__ partials, int n) {
    const int wave  = threadIdx.x >> 6;
    const int lane  = threadIdx.x & 63;
    const int gwave = blockIdx.x * WAVES_PER_BLOCK + wave;
    const int nwave = gridDim.x * WAVES_PER_BLOCK;

    float acc = 0.0f;  // sum over rows of (ssq - 1)^2, held on lane 0
    for (int row = gwave; row < n; row += nwave) {
        const float4* __restrict__ p =
            reinterpret_cast<const float4*>(d + (size_t)row * K);
        float ssq = 0.0f;
        // K/4 = 512 float4 per row; 64 lanes -> 8 iterations, fully coalesced
#pragma unroll 8
        for (int i = lane; i < (K >> 2); i += 64) {
            float4 v = p[i];
            ssq += v.x * v.x + v.y * v.y + v.z * v.z + v.w * v.w;
        }
        // 64-lane butterfly reduce
#pragma unroll
        for (int off = 32; off >= 1; off >>= 1)
            ssq += __shfl_xor(ssq, off);
        if (lane == 0) {
            float t = ssq - 1.0f;
            acc += t * t;
        }
    }

    __shared__ float smem[WAVES_PER_BLOCK];
    if (lane == 0) smem[wave] = acc;
    __syncthreads();
    if (threadIdx.x == 0) {
        float b = 0.0f;
#pragma unroll
        for (int i = 0; i < WAVES_PER_BLOCK; ++i) b += smem[i];
        partials[blockIdx.x] = b;  // plain store: every slot written each call
    }
}

// Phase 2: one block reduces the GRID partials, applies sqrt and scale.
__global__ __launch_bounds__(BLOCK) void finalize_kernel(
    const float* __restrict__ partials, int np, float* __restrict__ out) {
    float acc = 0.0f;
    for (int i = threadIdx.x; i < np; i += BLOCK) acc += partials[i];
#pragma unroll
    for (int off = 32; off >= 1; off >>= 1)
        acc += __shfl_xor(acc, off);

    __shared__ float smem[WAVES_PER_BLOCK];
    const int wave = threadIdx.x >> 6;
    const int lane = threadIdx.x & 63;
    if (lane == 0) smem[wave] = acc;
    __syncthreads();
    if (threadIdx.x == 0) {
        float t = 0.0f;
#pragma unroll
        for (int i = 0; i < WAVES_PER_BLOCK; ++i) t += smem[i];
        out[0] = 0.001f * sqrtf(t);
    }
}

extern "C" void kernel_launch(void* const* d_in, const int* in_sizes, int n_in,
                              void* d_out, int out_size, void* d_ws, size_t ws_size,
                              hipStream_t stream) {
    const float* d = (const float*)d_in[0];
    float* out = (float*)d_out;
    float* partials = (float*)d_ws;  // GRID floats of scratch

    const int n = in_sizes[0] / K;  // 16384 rows

    row_ssq_kernel<<<GRID, BLOCK, 0, stream>>>(d, partials, n);
    finalize_kernel<<<1, BLOCK, 0, stream>>>(partials, GRID, out);
}